// Round 1
// 361.551 us; speedup vs baseline: 1.1042x; 1.1042x over previous
//
#include <hip/hip_runtime.h>
#include <math.h>

// Problem constants
#define BATCH 4
#define C 256
#define H 128
#define W 128
#define HW (H * W)          // 16384
#define OH 256
#define OW 256
#define NPIX (BATCH * HW)        // 65536 input pixels
#define NPOS (BATCH * OH * OW)   // 262144 output positions
#define KSPLIT 4
#define KCH (C / KSPLIT)         // 64
#define CCHUNKS 4
__device__ __constant__ float OFF_FACTOR = 0.70710678118654752f; // sqrt(128/256)

// ---------------------------------------------------------------------------
// Kernel A: fused 1x1 conv + descriptor compute.
// Split-K x4 runs INSIDE the block (reduced through LDS) instead of via a
// global partial buffer (-16.8 MB round trip, -1 launch).
// Descriptors stored compact as float2 (xc,yc): 2.1 MB instead of 8.4 MB.
// Grid: 256 blocks x 256 threads; block owns 256 consecutive input pixels.
// ---------------------------------------------------------------------------
__global__ __launch_bounds__(256) void conv_desc_kernel(
    const float* __restrict__ x, const float* __restrict__ cw,
    const float* __restrict__ cb, float2* __restrict__ desc) {
    __shared__ float sw[8 * C];                            // 8 KB weights
    __shared__ __align__(16) float red[KSPLIT * 8 * 256];  // 32 KB partials
    int t = threadIdx.x;

    // stage all 8x256 weights (cw layout [o][c])
    #pragma unroll
    for (int i = 0; i < 8; ++i) sw[i * 256 + t] = cw[i * 256 + t];
    __syncthreads();

    // ---- phase 1: partial conv, thread (k, q) = (t>>6, t&63) ----
    int k = t >> 6;                   // ksplit chunk 0..3
    int q = t & 63;                   // float4-group within block
    int g4 = blockIdx.x * 64 + q;     // global float4-group
    int g = g4 * 4;                   // first pixel
    int b = g >> 14;
    int pix = g & (HW - 1);
    const float* xp = x + (size_t)b * C * HW + (size_t)(k * KCH) * HW + pix;

    float4 acc[8];
    #pragma unroll
    for (int o = 0; o < 8; ++o) acc[o] = make_float4(0.f, 0.f, 0.f, 0.f);

    #pragma unroll 8
    for (int c = 0; c < KCH; ++c) {
        float4 v = *(const float4*)(xp + (size_t)c * HW);
        #pragma unroll
        for (int o = 0; o < 8; ++o) {
            float wv = sw[o * C + k * KCH + c];
            acc[o].x += v.x * wv; acc[o].y += v.y * wv;
            acc[o].z += v.z * wv; acc[o].w += v.w * wv;
        }
    }

    // red layout: [k][o][pixel_in_block]  (pixel = q*4 + lane-of-float4)
    // writer: ds_write_b128 at stride-16B; reader: stride-4B conflict-free
    #pragma unroll
    for (int o = 0; o < 8; ++o)
        *(float4*)&red[((k * 8 + o) << 8) + (q << 2)] = acc[o];
    __syncthreads();

    // ---- phase 2: one thread per pixel, reduce K + emit descriptors ----
    int g2 = blockIdx.x * 256 + t;
    int b2 = g2 >> 14;
    int pix2 = g2 & (HW - 1);
    int h2 = pix2 >> 7;
    int w2 = pix2 & (W - 1);

    float s[8];
    #pragma unroll
    for (int o = 0; o < 8; ++o) {
        float a = cb[o];
        #pragma unroll
        for (int kk = 0; kk < KSPLIT; ++kk)
            a += red[((kk * 8 + o) << 8) + t];
        s[o] = a;
    }

    // offset-channel j in 0..3: sx = j&1, sy = j>>1
    // xc = OFF*s[j] + w + 0.5*sx ; yc = OFF*s[4+j] + h + 0.5*sy
    #pragma unroll
    for (int sy = 0; sy < 2; ++sy) {
        int j0 = sy * 2;
        float yb = (float)h2 + 0.5f * (float)sy;
        float xc0 = OFF_FACTOR * s[j0]     + (float)w2;
        float yc0 = OFF_FACTOR * s[4 + j0] + yb;
        float xc1 = OFF_FACTOR * s[j0 + 1] + (float)w2 + 0.5f;
        float yc1 = OFF_FACTOR * s[5 + j0] + yb;
        int p = (b2 * OH + 2 * h2 + sy) * OW + 2 * w2;   // even -> 16B aligned
        *(float4*)&desc[p] = make_float4(xc0, yc0, xc1, yc1);
    }
}

// ---------------------------------------------------------------------------
// Kernel B: bilinear gather. Block = (b, h_in, c-chunk of 64); 256 threads=ow.
// Descriptors decoded from compact float2 once per thread (amortized over
// 128 output elements). Output written with non-temporal stores so the
// 268 MB stream doesn't evict x from L2/L3.
// ---------------------------------------------------------------------------
__global__ __launch_bounds__(256) void sample_kernel(
    const float* __restrict__ x, const float2* __restrict__ desc,
    float* __restrict__ out) {
    int t = threadIdx.x;               // ow
    int lin = blockIdx.x;              // 0..2047
    // round-robin XCD assignment (lin % 8) -> give each XCD a contiguous band
    int ord = (lin & 7) * 256 + (lin >> 3);
    int cchunk = ord & 3;
    int h = (ord >> 2) & (H - 1);
    int b = ord >> 9;

    int oh0 = 2 * h, oh1 = 2 * h + 1;
    int p0 = (b * OH + oh0) * OW + t;
    int p1 = (b * OH + oh1) * OW + t;
    float2 d0 = desc[p0];
    float2 d1 = desc[p1];

    int4 ia, ib; float4 wa, wb;
    {
        float x0f = floorf(d0.x), y0f = floorf(d0.y);
        float fx = d0.x - x0f, fy = d0.y - y0f;
        int x0 = (int)x0f, y0 = (int)y0f;
        int x0i = min(max(x0, 0), W - 1), x1i = min(max(x0 + 1, 0), W - 1);
        int y0i = min(max(y0, 0), H - 1), y1i = min(max(y0 + 1, 0), H - 1);
        ia = make_int4(y0i * W + x0i, y0i * W + x1i,
                       y1i * W + x0i, y1i * W + x1i);
        wa = make_float4((1.f - fx) * (1.f - fy), fx * (1.f - fy),
                         (1.f - fx) * fy,         fx * fy);
    }
    {
        float x0f = floorf(d1.x), y0f = floorf(d1.y);
        float fx = d1.x - x0f, fy = d1.y - y0f;
        int x0 = (int)x0f, y0 = (int)y0f;
        int x0i = min(max(x0, 0), W - 1), x1i = min(max(x0 + 1, 0), W - 1);
        int y0i = min(max(y0, 0), H - 1), y1i = min(max(y0 + 1, 0), H - 1);
        ib = make_int4(y0i * W + x0i, y0i * W + x1i,
                       y1i * W + x0i, y1i * W + x1i);
        wb = make_float4((1.f - fx) * (1.f - fy), fx * (1.f - fy),
                         (1.f - fx) * fy,         fx * fy);
    }

    int c0 = cchunk * 64;
    const float* xp = x + (size_t)b * C * HW + (size_t)c0 * HW;
    float* op = out + (((size_t)(b * C + c0) * OH + oh0) * OW) + t;

    #pragma unroll 2
    for (int c = 0; c < 64; ++c) {
        const float* pl = xp + (size_t)c * HW;
        float v0 = pl[ia.x] * wa.x + pl[ia.y] * wa.y +
                   pl[ia.z] * wa.z + pl[ia.w] * wa.w;
        float v1 = pl[ib.x] * wb.x + pl[ib.y] * wb.y +
                   pl[ib.z] * wb.z + pl[ib.w] * wb.w;
        float* o0 = op + (size_t)c * (OH * OW);
        __builtin_nontemporal_store(v0, o0);
        __builtin_nontemporal_store(v1, o0 + OW);
    }
}

extern "C" void kernel_launch(void* const* d_in, const int* in_sizes, int n_in,
                              void* d_out, int out_size, void* d_ws, size_t ws_size,
                              hipStream_t stream) {
    const float* x  = (const float*)d_in[0];
    const float* cw = (const float*)d_in[1];
    const float* cb = (const float*)d_in[2];
    float* out = (float*)d_out;

    float2* desc = (float2*)d_ws;   // 2.1 MB only (was 16.8 MB)

    conv_desc_kernel<<<256, 256, 0, stream>>>(x, cw, cb, desc);
    sample_kernel<<<BATCH * H * CCHUNKS, 256, 0, stream>>>(x, desc, out);
}

// Round 3
// 314.810 us; speedup vs baseline: 1.2681x; 1.1485x over previous
//
#include <hip/hip_runtime.h>
#include <math.h>

// Problem constants
#define BATCH 4
#define C 256
#define H 128
#define W 128
#define HW (H * W)          // 16384
#define OH 256
#define OW 256
#define KSPLIT 4
#define KCH (C / KSPLIT)         // 64
#define SCH 32                   // channels per sample block
#define NCHUNK (C / SCH)         // 8
__device__ __constant__ float OFF_FACTOR = 0.70710678118654752f; // sqrt(128/256)

typedef float __attribute__((ext_vector_type(2))) f32x2;  // nt-store-compatible

// ---------------------------------------------------------------------------
// Kernel A: fused 1x1 conv + descriptor compute (unchanged from R1 — verified).
// Grid: 256 blocks x 256 threads; block owns 256 consecutive input pixels.
// ---------------------------------------------------------------------------
__global__ __launch_bounds__(256) void conv_desc_kernel(
    const float* __restrict__ x, const float* __restrict__ cw,
    const float* __restrict__ cb, float2* __restrict__ desc) {
    __shared__ float sw[8 * C];                            // 8 KB weights
    __shared__ __align__(16) float red[KSPLIT * 8 * 256];  // 32 KB partials
    int t = threadIdx.x;

    #pragma unroll
    for (int i = 0; i < 8; ++i) sw[i * 256 + t] = cw[i * 256 + t];
    __syncthreads();

    int k = t >> 6;
    int q = t & 63;
    int g4 = blockIdx.x * 64 + q;
    int g = g4 * 4;
    int b = g >> 14;
    int pix = g & (HW - 1);
    const float* xp = x + (size_t)b * C * HW + (size_t)(k * KCH) * HW + pix;

    float4 acc[8];
    #pragma unroll
    for (int o = 0; o < 8; ++o) acc[o] = make_float4(0.f, 0.f, 0.f, 0.f);

    #pragma unroll 8
    for (int c = 0; c < KCH; ++c) {
        float4 v = *(const float4*)(xp + (size_t)c * HW);
        #pragma unroll
        for (int o = 0; o < 8; ++o) {
            float wv = sw[o * C + k * KCH + c];
            acc[o].x += v.x * wv; acc[o].y += v.y * wv;
            acc[o].z += v.z * wv; acc[o].w += v.w * wv;
        }
    }

    #pragma unroll
    for (int o = 0; o < 8; ++o)
        *(float4*)&red[((k * 8 + o) << 8) + (q << 2)] = acc[o];
    __syncthreads();

    int g2 = blockIdx.x * 256 + t;
    int b2 = g2 >> 14;
    int pix2 = g2 & (HW - 1);
    int h2 = pix2 >> 7;
    int w2 = pix2 & (W - 1);

    float s[8];
    #pragma unroll
    for (int o = 0; o < 8; ++o) {
        float a = cb[o];
        #pragma unroll
        for (int kk = 0; kk < KSPLIT; ++kk)
            a += red[((kk * 8 + o) << 8) + t];
        s[o] = a;
    }

    #pragma unroll
    for (int sy = 0; sy < 2; ++sy) {
        int j0 = sy * 2;
        float yb = (float)h2 + 0.5f * (float)sy;
        float xc0 = OFF_FACTOR * s[j0]     + (float)w2;
        float yc0 = OFF_FACTOR * s[4 + j0] + yb;
        float xc1 = OFF_FACTOR * s[j0 + 1] + (float)w2 + 0.5f;
        float yc1 = OFF_FACTOR * s[5 + j0] + yb;
        int p = (b2 * OH + 2 * h2 + sy) * OW + 2 * w2;   // even -> 16B aligned
        *(float4*)&desc[p] = make_float4(xc0, yc0, xc1, yc1);
    }
}

// ---------------------------------------------------------------------------
// Kernel B: bilinear gather THROUGH LDS.
// Block = (b, input row-pair h0, 32-channel chunk). 256 threads = one input
// pixel each (2 rows x 128 cols); each produces its 4 output sub-samples.
// Rows [h0-1, h0+2] x 32 ch staged coalesced into 64 KB LDS (2 blocks/CU);
// 16 taps/channel gathered with ds_read (banks = x%32, conflict-free).
// Taps outside the 4-row window (~never: needs >4.4 sigma offset) fall back
// to an exact global-gather path per wave.
// XCD swizzle: each XCD owns 4 (b,chunk) combos, h ascending -> 2 MB
// working set L2-resident, halo rows L2-hit.
// ---------------------------------------------------------------------------
__global__ __launch_bounds__(256) void sample_kernel(
    const float* __restrict__ x, const float4* __restrict__ desc4,
    float* __restrict__ out) {
    __shared__ __align__(16) float tile[SCH * 4 * W];   // [c][i][col], 64 KB
    int t = threadIdx.x;
    int lin = blockIdx.x;                 // 0..2047
    int xcd = lin & 7;
    int i8  = lin >> 3;                   // 0..255
    int combo = xcd * 4 + (i8 >> 6);      // 0..31 = (b, chunk)
    int hblk  = i8 & 63;
    int b = combo >> 3;
    int chunk = combo & 7;
    int h0 = hblk * 2;
    int c0 = chunk * SCH;

    const float* xb = x + (size_t)b * C * HW + (size_t)c0 * HW;

    // ---- stage rows clamp(h0-1 .. h0+2) x 32 ch, fully coalesced float4 ----
    #pragma unroll
    for (int j = 0; j < 16; ++j) {
        int idx = (j * 256 + t) * 4;      // float index in tile (16B aligned)
        int c   = idx >> 9;               // /512
        int i   = (idx >> 7) & 3;
        int col = idx & 127;
        int row = min(max(h0 - 1 + i, 0), H - 1);
        *(float4*)&tile[idx] =
            *(const float4*)(xb + (size_t)c * HW + row * W + col);
    }

    // ---- per-thread descriptor decode (once, reused over 32 channels) ----
    int hr = t >> 7;                      // 0/1: which input row
    int w  = t & 127;                     // input col
    int hh = h0 + hr;

    float4 d0 = desc4[(((size_t)b * OH + 2 * hh) * OW + 2 * w) >> 1];
    float4 d1 = desc4[(((size_t)b * OH + 2 * hh + 1) * OW + 2 * w) >> 1];

    int   loff[4][4];
    float wt[4][4];
    bool allok = true;
    float xcs[4] = {d0.x, d0.z, d1.x, d1.z};
    float ycs[4] = {d0.y, d0.w, d1.y, d1.w};
    #pragma unroll
    for (int j = 0; j < 4; ++j) {
        float xc = xcs[j], yc = ycs[j];
        float x0f = floorf(xc), y0f = floorf(yc);
        float fx = xc - x0f, fy = yc - y0f;
        int x0 = (int)x0f, y0 = (int)y0f;
        int x0i = min(max(x0, 0), W - 1), x1i = min(max(x0 + 1, 0), W - 1);
        int y0i = min(max(y0, 0), H - 1), y1i = min(max(y0 + 1, 0), H - 1);
        int iy0 = y0i - h0 + 1, iy1 = y1i - h0 + 1;   // LDS row index
        allok = allok && ((unsigned)iy0 <= 3u) && ((unsigned)iy1 <= 3u);
        loff[j][0] = iy0 * W + x0i;  loff[j][1] = iy0 * W + x1i;
        loff[j][2] = iy1 * W + x0i;  loff[j][3] = iy1 * W + x1i;
        wt[j][0] = (1.f - fx) * (1.f - fy); wt[j][1] = fx * (1.f - fy);
        wt[j][2] = (1.f - fx) * fy;         wt[j][3] = fx * fy;
    }

    __syncthreads();

    float* op0 = out + (((size_t)(b * C + c0) * OH + 2 * hh) * OW) + 2 * w;

    if (__all(allok)) {
        // ---- fast path: all taps in the staged window ----
        #pragma unroll 4
        for (int c = 0; c < SCH; ++c) {
            const float* tl = tile + c * (4 * W);
            float v[4];
            #pragma unroll
            for (int j = 0; j < 4; ++j)
                v[j] = tl[loff[j][0]] * wt[j][0] + tl[loff[j][1]] * wt[j][1] +
                       tl[loff[j][2]] * wt[j][2] + tl[loff[j][3]] * wt[j][3];
            float* op = op0 + (size_t)c * (OH * OW);
            f32x2 r0 = {v[0], v[1]};
            f32x2 r1 = {v[2], v[3]};
            __builtin_nontemporal_store(r0, (f32x2*)op);
            __builtin_nontemporal_store(r1, (f32x2*)(op + OW));
        }
    } else {
        // ---- exact fallback: gather straight from global x ----
        int rebase = (h0 - 1) * W;        // loff + rebase == y*W + x
        #pragma unroll 2
        for (int c = 0; c < SCH; ++c) {
            const float* pl = xb + (size_t)c * HW;
            float v[4];
            #pragma unroll
            for (int j = 0; j < 4; ++j)
                v[j] = pl[loff[j][0] + rebase] * wt[j][0] +
                       pl[loff[j][1] + rebase] * wt[j][1] +
                       pl[loff[j][2] + rebase] * wt[j][2] +
                       pl[loff[j][3] + rebase] * wt[j][3];
            float* op = op0 + (size_t)c * (OH * OW);
            f32x2 r0 = {v[0], v[1]};
            f32x2 r1 = {v[2], v[3]};
            __builtin_nontemporal_store(r0, (f32x2*)op);
            __builtin_nontemporal_store(r1, (f32x2*)(op + OW));
        }
    }
}

extern "C" void kernel_launch(void* const* d_in, const int* in_sizes, int n_in,
                              void* d_out, int out_size, void* d_ws, size_t ws_size,
                              hipStream_t stream) {
    const float* x  = (const float*)d_in[0];
    const float* cw = (const float*)d_in[1];
    const float* cb = (const float*)d_in[2];
    float* out = (float*)d_out;

    float2* desc = (float2*)d_ws;   // 2.1 MB

    conv_desc_kernel<<<256, 256, 0, stream>>>(x, cw, cb, desc);
    sample_kernel<<<BATCH * (H / 2) * NCHUNK, 256, 0, stream>>>(
        x, (const float4*)desc, out);
}

// Round 4
// 311.367 us; speedup vs baseline: 1.2821x; 1.0111x over previous
//
#include <hip/hip_runtime.h>
#include <math.h>

// Problem constants
#define BATCH 4
#define C 256
#define H 128
#define W 128
#define HW (H * W)          // 16384
#define OH 256
#define OW 256
#define KSPLIT 4
#define KCH (C / KSPLIT)         // 64
#define SCH 16                   // channels per sample block (32KB tile)
#define NCHUNK (C / SCH)         // 16
__device__ __constant__ float OFF_FACTOR = 0.70710678118654752f; // sqrt(128/256)

typedef float __attribute__((ext_vector_type(2))) f32x2;  // nt-store-compatible

// ---------------------------------------------------------------------------
// Kernel A: fused 1x1 conv + descriptor compute (unchanged — verified).
// Grid: 256 blocks x 256 threads; block owns 256 consecutive input pixels.
// ---------------------------------------------------------------------------
__global__ __launch_bounds__(256) void conv_desc_kernel(
    const float* __restrict__ x, const float* __restrict__ cw,
    const float* __restrict__ cb, float2* __restrict__ desc) {
    __shared__ float sw[8 * C];                            // 8 KB weights
    __shared__ __align__(16) float red[KSPLIT * 8 * 256];  // 32 KB partials
    int t = threadIdx.x;

    #pragma unroll
    for (int i = 0; i < 8; ++i) sw[i * 256 + t] = cw[i * 256 + t];
    __syncthreads();

    int k = t >> 6;
    int q = t & 63;
    int g4 = blockIdx.x * 64 + q;
    int g = g4 * 4;
    int b = g >> 14;
    int pix = g & (HW - 1);
    const float* xp = x + (size_t)b * C * HW + (size_t)(k * KCH) * HW + pix;

    float4 acc[8];
    #pragma unroll
    for (int o = 0; o < 8; ++o) acc[o] = make_float4(0.f, 0.f, 0.f, 0.f);

    #pragma unroll 8
    for (int c = 0; c < KCH; ++c) {
        float4 v = *(const float4*)(xp + (size_t)c * HW);
        #pragma unroll
        for (int o = 0; o < 8; ++o) {
            float wv = sw[o * C + k * KCH + c];
            acc[o].x += v.x * wv; acc[o].y += v.y * wv;
            acc[o].z += v.z * wv; acc[o].w += v.w * wv;
        }
    }

    #pragma unroll
    for (int o = 0; o < 8; ++o)
        *(float4*)&red[((k * 8 + o) << 8) + (q << 2)] = acc[o];
    __syncthreads();

    int g2 = blockIdx.x * 256 + t;
    int b2 = g2 >> 14;
    int pix2 = g2 & (HW - 1);
    int h2 = pix2 >> 7;
    int w2 = pix2 & (W - 1);

    float s[8];
    #pragma unroll
    for (int o = 0; o < 8; ++o) {
        float a = cb[o];
        #pragma unroll
        for (int kk = 0; kk < KSPLIT; ++kk)
            a += red[((kk * 8 + o) << 8) + t];
        s[o] = a;
    }

    #pragma unroll
    for (int sy = 0; sy < 2; ++sy) {
        int j0 = sy * 2;
        float yb = (float)h2 + 0.5f * (float)sy;
        float xc0 = OFF_FACTOR * s[j0]     + (float)w2;
        float yc0 = OFF_FACTOR * s[4 + j0] + yb;
        float xc1 = OFF_FACTOR * s[j0 + 1] + (float)w2 + 0.5f;
        float yc1 = OFF_FACTOR * s[5 + j0] + yb;
        int p = (b2 * OH + 2 * h2 + sy) * OW + 2 * w2;   // even -> 16B aligned
        *(float4*)&desc[p] = make_float4(xc0, yc0, xc1, yc1);
    }
}

// ---------------------------------------------------------------------------
// Kernel B: bilinear gather through LDS, v2.
// Changes vs R3: (1) clamp folded into weights so the 4 taps are statically
// {b, b+1, b+W, b+W+1} -> compiler merges pairs into ds_read2_b32 (8 LDS
// instrs/channel instead of 16); (2) SCH=16 -> 32KB tile, 5 blocks/CU,
// 20 waves/CU for phase overlap. Fallback path (taps outside 4-row window,
// ~4-sigma) gathers from global with the same folded taps.
// ---------------------------------------------------------------------------
__global__ __launch_bounds__(256) void sample_kernel(
    const float* __restrict__ x, const float4* __restrict__ desc4,
    float* __restrict__ out) {
    __shared__ __align__(16) float tile[SCH * 4 * W];   // [c][row][col], 32 KB
    int t = threadIdx.x;
    int lin = blockIdx.x;                 // 0..4095
    int xcd = lin & 7;
    int i8  = lin >> 3;                   // 0..511
    int combo = xcd * 8 + (i8 >> 6);      // 0..63 = (b, chunk)
    int hblk  = i8 & 63;
    int b = combo >> 4;
    int chunk = combo & 15;
    int h0 = hblk * 2;
    int c0 = chunk * SCH;

    const float* xb = x + (size_t)b * C * HW + (size_t)c0 * HW;

    // ---- stage rows clamp(h0-1 .. h0+2) x 16 ch, fully coalesced float4 ----
    #pragma unroll
    for (int j = 0; j < 8; ++j) {
        int idx = (j * 256 + t) * 4;      // float index in tile (16B aligned)
        int c   = idx >> 9;               // /512
        int i   = (idx >> 7) & 3;
        int col = idx & 127;
        int row = min(max(h0 - 1 + i, 0), H - 1);
        *(float4*)&tile[idx] =
            *(const float4*)(xb + (size_t)c * HW + row * W + col);
    }

    // ---- per-thread descriptor decode (once, reused over 16 channels) ----
    int hr = t >> 7;                      // 0/1: which input row
    int w  = t & 127;                     // input col
    int hh = h0 + hr;

    float4 d0 = desc4[(((size_t)b * OH + 2 * hh) * OW + 2 * w) >> 1];
    float4 d1 = desc4[(((size_t)b * OH + 2 * hh + 1) * OW + 2 * w) >> 1];

    int   loff[4];          // base tap: iy0*W + x0c (taps at +0,+1,+W,+W+1)
    float wt[4][4];
    bool allok = true;
    float xcs[4] = {d0.x, d0.z, d1.x, d1.z};
    float ycs[4] = {d0.y, d0.w, d1.y, d1.w};
    #pragma unroll
    for (int j = 0; j < 4; ++j) {
        float xc = xcs[j], yc = ycs[j];
        float x0f = floorf(xc), y0f = floorf(yc);
        int x0 = (int)x0f, y0 = (int)y0f;
        // fold clamp into weights: taps become x0c..x0c+1, y0c..y0c+1
        int x0c = min(max(x0, 0), W - 2);
        int y0c = min(max(y0, 0), H - 2);
        float fx = (x0 < 0) ? 0.f : ((x0 > W - 2) ? 1.f : xc - x0f);
        float fy = (y0 < 0) ? 0.f : ((y0 > H - 2) ? 1.f : yc - y0f);
        int iy0 = y0c - h0 + 1;                       // LDS row of top tap
        allok = allok && ((unsigned)iy0 <= 2u);       // rows iy0, iy0+1 in 0..3
        loff[j] = iy0 * W + x0c;
        wt[j][0] = (1.f - fx) * (1.f - fy); wt[j][1] = fx * (1.f - fy);
        wt[j][2] = (1.f - fx) * fy;         wt[j][3] = fx * fy;
    }

    __syncthreads();

    float* op0 = out + (((size_t)(b * C + c0) * OH + 2 * hh) * OW) + 2 * w;

    if (__all(allok)) {
        // ---- fast path: taps {b,b+1,b+W,b+W+1} -> ds_read2_b32 pairs ----
        #pragma unroll 4
        for (int c = 0; c < SCH; ++c) {
            const float* tl = tile + c * (4 * W);
            float v[4];
            #pragma unroll
            for (int j = 0; j < 4; ++j) {
                int bj = loff[j];
                float t00 = tl[bj],     t01 = tl[bj + 1];
                float t10 = tl[bj + W], t11 = tl[bj + W + 1];
                v[j] = t00 * wt[j][0] + t01 * wt[j][1] +
                       t10 * wt[j][2] + t11 * wt[j][3];
            }
            float* op = op0 + (size_t)c * (OH * OW);
            f32x2 r0 = {v[0], v[1]};
            f32x2 r1 = {v[2], v[3]};
            __builtin_nontemporal_store(r0, (f32x2*)op);
            __builtin_nontemporal_store(r1, (f32x2*)(op + OW));
        }
    } else {
        // ---- exact fallback: gather straight from global x ----
        int rebase = (h0 - 1) * W;        // loff + rebase == y0c*W + x0c
        #pragma unroll 2
        for (int c = 0; c < SCH; ++c) {
            const float* pl = xb + (size_t)c * HW;
            float v[4];
            #pragma unroll
            for (int j = 0; j < 4; ++j) {
                int bj = loff[j] + rebase;
                v[j] = pl[bj]         * wt[j][0] + pl[bj + 1]     * wt[j][1] +
                       pl[bj + W]     * wt[j][2] + pl[bj + W + 1] * wt[j][3];
            }
            float* op = op0 + (size_t)c * (OH * OW);
            f32x2 r0 = {v[0], v[1]};
            f32x2 r1 = {v[2], v[3]};
            __builtin_nontemporal_store(r0, (f32x2*)op);
            __builtin_nontemporal_store(r1, (f32x2*)(op + OW));
        }
    }
}

extern "C" void kernel_launch(void* const* d_in, const int* in_sizes, int n_in,
                              void* d_out, int out_size, void* d_ws, size_t ws_size,
                              hipStream_t stream) {
    const float* x  = (const float*)d_in[0];
    const float* cw = (const float*)d_in[1];
    const float* cb = (const float*)d_in[2];
    float* out = (float*)d_out;

    float2* desc = (float2*)d_ws;   // 2.1 MB

    conv_desc_kernel<<<256, 256, 0, stream>>>(x, cw, cb, desc);
    sample_kernel<<<BATCH * (H / 2) * NCHUNK, 256, 0, stream>>>(
        x, (const float4*)desc, out);
}